// Round 5
// baseline (1069.313 us; speedup 1.0000x reference)
//
#include <hip/hip_runtime.h>
#include <stdint.h>

#define D 64          // embedding dim
#define SH_I 8        // item rows per dest-bucket = 256
#define SH_U 9        // user rows per dest-bucket = 512
#define EPT 4         // edges per thread in passA
#define TILE 2048     // 512 threads * EPT
#define TSH 13        // source tile = 8192 rows = 2MB of embeddings
#define LBINS 4608    // max (rows-per-bucket * T) bins, padded
#define NPT 9         // LBINS / 512

typedef unsigned long long u64;
typedef unsigned int u32;
typedef float f32x4 __attribute__((ext_vector_type(4)));   // native vec for NT ld/st

// ---------------- helpers ----------------

// exclusive prefix over 512-thread block (uses one __syncthreads pair)
__device__ __forceinline__ int block_excl_scan512(int v, int* wsum) {
    int tid = threadIdx.x, lane = tid & 63, wid = tid >> 6;
    int x = v;
    #pragma unroll
    for (int d = 1; d < 64; d <<= 1) { int t = __shfl_up(x, d, 64); if (lane >= d) x += t; }
    if (lane == 63) wsum[wid] = x;
    __syncthreads();
    if (tid < 8) {
        int y = wsum[tid];
        #pragma unroll
        for (int d = 1; d < 8; d <<= 1) { int t = __shfl_up(y, d, 8); if (tid >= d) y += t; }
        wsum[tid] = y;
    }
    __syncthreads();
    return ((wid > 0) ? wsum[wid - 1] : 0) + x - v;
}

// ---------------- CSR build ----------------

__global__ __launch_bounds__(512)
void init_cursors_kernel(int* cur_i, int nb_i, int cap_i,
                         int* cur_u, int nb_u, int cap_u) {
    int t = threadIdx.x;
    if (t < nb_i) cur_i[t] = t * cap_i;
    if (t < nb_u) cur_u[t] = t * cap_u;
}

// Bin edges by destination bucket for both directions in one pass.
// Record (8B): [val:32][src << SH | dst_in_bucket]
__global__ __launch_bounds__(512)
void passA_kernel(const int* __restrict__ eu, const int* __restrict__ ei,
                  const float* __restrict__ ev, int E,
                  int* __restrict__ cur_i, int nb_i,
                  int* __restrict__ cur_u, int nb_u,
                  u64* __restrict__ stg_i, u64* __restrict__ stg_u) {
    __shared__ int cnt_i[256], cnt_u[256];
    __shared__ int base_i[256], base_u[256];
    int tid = threadIdx.x;
    long tile0 = (long)blockIdx.x * TILE;
    if (tid < 256) { cnt_i[tid] = 0; cnt_u[tid] = 0; }
    __syncthreads();
    int uu[EPT], ii[EPT], lo_i[EPT], lo_u[EPT];
    float vv[EPT];
    #pragma unroll
    for (int j = 0; j < EPT; ++j) {
        long e = tile0 + tid + j * 512;
        if (e < E) {
            uu[j] = eu[e]; ii[j] = ei[e]; vv[j] = ev[e];
            lo_i[j] = atomicAdd(&cnt_i[ii[j] >> SH_I], 1);
            lo_u[j] = atomicAdd(&cnt_u[uu[j] >> SH_U], 1);
        } else {
            uu[j] = -1;
        }
    }
    __syncthreads();
    if (tid < nb_i && cnt_i[tid]) base_i[tid] = atomicAdd(&cur_i[tid], cnt_i[tid]);
    if (tid < nb_u && cnt_u[tid]) base_u[tid] = atomicAdd(&cur_u[tid], cnt_u[tid]);
    __syncthreads();
    #pragma unroll
    for (int j = 0; j < EPT; ++j) {
        if (uu[j] >= 0) {
            u64 vb = (u64)__float_as_uint(vv[j]) << 32;
            int bi = ii[j] >> SH_I;
            stg_i[base_i[bi] + lo_i[j]] =
                vb | ((u32)uu[j] << SH_I) | (u32)(ii[j] & ((1 << SH_I) - 1));
            int bu = uu[j] >> SH_U;
            stg_u[base_u[bu] + lo_u[j]] =
                vb | ((u32)ii[j] << SH_U) | (u32)(uu[j] & ((1 << SH_U) - 1));
        }
    }
}

// exclusive scan of per-bucket counts -> bucket edge bases; write rowp2 sentinel
__global__ __launch_bounds__(512)
void bucket_scan_kernel(const int* __restrict__ cur, int nb, int cap,
                        int* __restrict__ bbase,
                        int* __restrict__ rowp2_sent, long sent_idx, int E) {
    __shared__ int wsum[8];
    int tid = threadIdx.x;
    int v = (tid < nb) ? (cur[tid] - tid * cap) : 0;
    int excl = block_excl_scan512(v, wsum);
    if (tid < nb) bbase[tid] = excl;
    if (tid == 0) rowp2_sent[sent_idx] = E;
}

// Per bucket: LDS (row,tile)-histogram + block scan -> rowptr2; place into final CSR.
__global__ __launch_bounds__(512)
void passB_kernel(int nb_i, int cap_i, int N_i, int T_u,
                  int nb_u, int cap_u, int N_u, int T_i,
                  const int* __restrict__ cur_i, const int* __restrict__ cur_u,
                  const int* __restrict__ bb_i, const int* __restrict__ bb_u,
                  const u64* __restrict__ stg_i, const u64* __restrict__ stg_u,
                  int* __restrict__ rowp2_i, int* __restrict__ rowp2_u,
                  int2* __restrict__ csr_i, int2* __restrict__ csr_u) {
    __shared__ int lcnt[LBINS];
    __shared__ int wsum[8];
    int b = blockIdx.x;
    int dir_item = (b < nb_i);
    int bb = dir_item ? b : b - nb_i;
    int SH = dir_item ? SH_I : SH_U;
    int T  = dir_item ? T_u : T_i;          // tiles over SOURCE side
    int cap = dir_item ? cap_i : cap_u;
    int N = dir_item ? N_i : N_u;
    const u64* stg = dir_item ? stg_i : stg_u;
    int ebase = dir_item ? bb_i[bb] : bb_u[bb];
    int scount = (dir_item ? cur_i[bb] : cur_u[bb]) - bb * cap;
    int* rowp2 = dir_item ? rowp2_i : rowp2_u;
    int2* csr = dir_item ? csr_i : csr_u;

    int rows0 = bb << SH;
    int nrows = min(1 << SH, N - rows0);
    int nbins = nrows * T;
    int sbeg = bb * cap;
    int tid = threadIdx.x;
    int mask = (1 << SH) - 1;

    for (int q = tid; q < LBINS; q += 512) lcnt[q] = 0;
    __syncthreads();
    for (int k = tid; k < scount; k += 512) {
        u64 rec = stg[sbeg + k];
        int rin = (int)((u32)rec & mask);
        int src = (int)(((u32)rec) >> SH);
        atomicAdd(&lcnt[rin * T + (src >> TSH)], 1);
    }
    __syncthreads();
    // exclusive scan over lcnt[0..LBINS): each thread owns NPT consecutive bins
    int loc[NPT];
    int run = 0;
    int base = tid * NPT;
    #pragma unroll
    for (int q = 0; q < NPT; ++q) { loc[q] = run; run += lcnt[base + q]; }
    int excl = block_excl_scan512(run, wsum);
    #pragma unroll
    for (int q = 0; q < NPT; ++q) lcnt[base + q] = excl + loc[q];
    __syncthreads();
    // rowptr2: bins are (rin,t) row-major and rows0 is bucket-contiguous
    for (int q = tid; q < nbins; q += 512)
        rowp2[(size_t)rows0 * T + q] = ebase + lcnt[q];
    __syncthreads();
    for (int k = tid; k < scount; k += 512) {
        u64 rec = stg[sbeg + k];
        int rin = (int)((u32)rec & mask);
        int src = (int)(((u32)rec) >> SH);
        int bin = rin * T + (src >> TSH);
        int pos = ebase + atomicAdd(&lcnt[bin], 1);
        csr[pos] = make_int2(src, (int)(rec >> 32));
    }
}

// ---------------- propagation ----------------

// All-rows-resident tiled SpMM: 4 lanes per row, acc in registers, loop over
// source tiles with a block barrier per tile (soft-lockstep across blocks ->
// the ~2MB source tile stays L2-resident on every XCD).
// dst[row] = sum val*src[s]; sum_out[row] = sum_in[row] + dst[row]
__global__ __launch_bounds__(256, 8)
void spmm2_kernel(const int* __restrict__ rowp2, const int2* __restrict__ csr,
                  const float* __restrict__ src_emb, float* __restrict__ dst_emb,
                  const float* __restrict__ sum_in, float* __restrict__ sum_out,
                  int nrows, int T) {
    int gid = blockIdx.x * 256 + threadIdx.x;
    int row = gid >> 2;
    int sub = gid & 3;
    bool act = row < nrows;
    f32x4 a0 = {0,0,0,0}, a1 = {0,0,0,0}, a2 = {0,0,0,0}, a3 = {0,0,0,0};
    const f32x4* SB = (const f32x4*)src_emb + sub;
    long rb = (long)row * T;
    for (int t = 0; t < T; ++t) {
        if (act) {
            int k0 = rowp2[rb + t];
            int k1 = rowp2[rb + t + 1];
            for (int k = k0; k < k1; ++k) {
                u64 rr = __builtin_nontemporal_load((const u64*)(csr + k));
                int s = (int)(u32)rr;
                float v = __uint_as_float((u32)(rr >> 32));
                const f32x4* sp = SB + (size_t)s * 16;
                f32x4 x0 = sp[0], x1 = sp[4], x2 = sp[8], x3 = sp[12];
                a0 += v * x0;
                a1 += v * x1;
                a2 += v * x2;
                a3 += v * x3;
            }
        }
        __syncthreads();   // soft-lockstep: keep all blocks on the same tile
    }
    if (act) {
        f32x4* dp = (f32x4*)(dst_emb + (size_t)row * D);
        const f32x4* si = (const f32x4*)(sum_in + (size_t)row * D);
        f32x4* so = (f32x4*)(sum_out + (size_t)row * D);
        __builtin_nontemporal_store(a0, dp + sub);
        __builtin_nontemporal_store(a1, dp + sub + 4);
        __builtin_nontemporal_store(a2, dp + sub + 8);
        __builtin_nontemporal_store(a3, dp + sub + 12);
        f32x4 s0 = si[sub], s1 = si[sub + 4], s2 = si[sub + 8], s3 = si[sub + 12];
        s0 += a0; s1 += a1; s2 += a2; s3 += a3;
        __builtin_nontemporal_store(s0, so + sub);
        __builtin_nontemporal_store(s1, so + sub + 4);
        __builtin_nontemporal_store(s2, so + sub + 8);
        __builtin_nontemporal_store(s3, so + sub + 12);
    }
}

__global__ __launch_bounds__(256)
void score_kernel(const float* __restrict__ sum_u, const float* __restrict__ sum_i,
                  const int* __restrict__ users, const int* __restrict__ items,
                  float* __restrict__ out, int B, float inv2) {
    int gid = blockIdx.x * blockDim.x + threadIdx.x;
    int b = gid >> 4;
    int lane = gid & 15;
    if (b >= B) return;
    int u = users[b], it = items[b];
    float4 a = ((const float4*)(sum_u + (size_t)u * D))[lane];
    float4 c = ((const float4*)(sum_i + (size_t)it * D))[lane];
    float d = a.x * c.x + a.y * c.y + a.z * c.z + a.w * c.w;
    #pragma unroll
    for (int m = 1; m < 16; m <<= 1) d += __shfl_xor(d, m, 64);
    if (lane == 0) out[b] = d * inv2;
}

// ---------------- launch ----------------

extern "C" void kernel_launch(void* const* d_in, const int* in_sizes, int n_in,
                              void* d_out, int out_size, void* d_ws, size_t ws_size,
                              hipStream_t stream) {
    const float* user_emb = (const float*)d_in[0];
    const float* item_emb = (const float*)d_in[1];
    const float* edge_vals = (const float*)d_in[2];
    const int* edge_u = (const int*)d_in[3];
    const int* edge_i = (const int*)d_in[4];
    const int* users = (const int*)d_in[5];
    const int* items = (const int*)d_in[6];
    float* out = (float*)d_out;

    const int U = in_sizes[0] / D;
    const int I = in_sizes[1] / D;
    const int E = in_sizes[2];
    const int B = in_sizes[5];

    const int nb_i = (I + (1 << SH_I) - 1) >> SH_I;   // dest-item buckets
    const int nb_u = (U + (1 << SH_U) - 1) >> SH_U;   // dest-user buckets
    const int T_u = (U + (1 << TSH) - 1) >> TSH;      // source tiles over users (13)
    const int T_i = (I + (1 << TSH) - 1) >> TSH;      // source tiles over items (7)
    const int cap_i = ((E / nb_i + E / (16 * nb_i) + 512 + 63) / 64) * 64;
    const int cap_u = ((E / nb_u + E / (16 * nb_u) + 512 + 63) / 64) * 64;

    // carve workspace (256B aligned)
    char* p = (char*)d_ws;
    size_t off = 0;
    auto alloc = [&](size_t bytes) -> char* {
        char* r = p + off;
        off = (off + bytes + 255) & ~(size_t)255;
        return r;
    };
    float* sum_u  = (float*)alloc((size_t)U * D * 4);
    float* sum_i  = (float*)alloc((size_t)I * D * 4);
    float* euA    = (float*)alloc((size_t)U * D * 4);
    float* eiA    = (float*)alloc((size_t)I * D * 4);
    int2* csr_u   = (int2*)alloc((size_t)(E + 16) * 8);
    int2* csr_i   = (int2*)alloc((size_t)(E + 16) * 8);
    int* rowp2_u  = (int*)alloc(((size_t)U * T_i + 1) * 4);
    int* rowp2_i  = (int*)alloc(((size_t)I * T_u + 1) * 4);
    int* cur_i    = (int*)alloc((size_t)nb_i * 4);
    int* cur_u    = (int*)alloc((size_t)nb_u * 4);
    int* bb_i     = (int*)alloc((size_t)nb_i * 4);
    int* bb_u     = (int*)alloc((size_t)nb_u * 4);
    u64* stg_i    = (u64*)alloc((size_t)nb_i * cap_i * 8);
    u64* stg_u    = (u64*)alloc((size_t)nb_u * cap_u * 8);
    // stg_* are dead after passB: alias the layer ping-pong buffers over them
    float* euB = (float*)stg_i;   // U*D*4 = 25.6MB <= nb_i*cap_i*8 (~28MB)
    float* eiB = (float*)stg_u;   // I*D*4 = 12.8MB
    if (off > ws_size) return;    // workspace too small -> fail loudly

    // 1. CSR build, grouped by (dest-row, source-tile)
    init_cursors_kernel<<<1, 512, 0, stream>>>(cur_i, nb_i, cap_i, cur_u, nb_u, cap_u);
    int tiles = (int)((E + TILE - 1) / TILE);
    passA_kernel<<<tiles, 512, 0, stream>>>(edge_u, edge_i, edge_vals, E,
                                            cur_i, nb_i, cur_u, nb_u, stg_i, stg_u);
    bucket_scan_kernel<<<1, 512, 0, stream>>>(cur_i, nb_i, cap_i, bb_i,
                                              rowp2_i, (long)I * T_u, E);
    bucket_scan_kernel<<<1, 512, 0, stream>>>(cur_u, nb_u, cap_u, bb_u,
                                              rowp2_u, (long)U * T_i, E);
    passB_kernel<<<nb_i + nb_u, 512, 0, stream>>>(nb_i, cap_i, I, T_u,
                                                  nb_u, cap_u, U, T_i,
                                                  cur_i, cur_u, bb_i, bb_u,
                                                  stg_i, stg_u, rowp2_i, rowp2_u,
                                                  csr_i, csr_u);

    // 2. three propagation layers (Jacobi: both SpMMs read the old layer)
    int gi = (I * 4 + 255) / 256;   // 782 blocks  (all co-resident)
    int gu = (U * 4 + 255) / 256;   // 1563 blocks (all co-resident)
    // layer 0 (sum_in = original embeddings -> fuses the sum init)
    spmm2_kernel<<<gi, 256, 0, stream>>>(rowp2_i, csr_i, user_emb, eiA, item_emb, sum_i, I, T_u);
    spmm2_kernel<<<gu, 256, 0, stream>>>(rowp2_u, csr_u, item_emb, euA, user_emb, sum_u, U, T_i);
    // layer 1
    spmm2_kernel<<<gi, 256, 0, stream>>>(rowp2_i, csr_i, euA, eiB, sum_i, sum_i, I, T_u);
    spmm2_kernel<<<gu, 256, 0, stream>>>(rowp2_u, csr_u, eiA, euB, sum_u, sum_u, U, T_i);
    // layer 2
    spmm2_kernel<<<gi, 256, 0, stream>>>(rowp2_i, csr_i, euB, eiA, sum_i, sum_i, I, T_u);
    spmm2_kernel<<<gu, 256, 0, stream>>>(rowp2_u, csr_u, eiB, euA, sum_u, sum_u, U, T_i);

    // 3. final scores: inv^2 * dot(sum_u[u], sum_i[i]), inv = 1/(L+1) = 1/4
    int blk_s = (B * 16 + 255) / 256;
    score_kernel<<<blk_s, 256, 0, stream>>>(sum_u, sum_i, users, items, out, B, 0.0625f);
}